// Round 5
// baseline (5861.230 us; speedup 1.0000x reference)
//
#include <hip/hip_runtime.h>
#include <hip/hip_bf16.h>

#define BB 4
#define NN 8192
#define CC 64
#define SS 2048
#define GG 32
#define C2V 128
#define HHV 512

typedef unsigned long long u64;
typedef unsigned int u32;

// ---------------------------------------------------------------- transpose fea (B,C,N)->(B,N,C)
__global__ void k_transpose_fea(const float* __restrict__ in, float* __restrict__ out) {
  __shared__ float tile[32][33];
  const int b = blockIdx.z;
  const int n0 = blockIdx.x * 32, c0 = blockIdx.y * 32;
  const int tx = threadIdx.x, ty = threadIdx.y;
  const float* src = in + (size_t)b * CC * NN;
#pragma unroll
  for (int i = 0; i < 32; i += 8)
    tile[ty + i][tx] = src[(size_t)(c0 + ty + i) * NN + n0 + tx];
  __syncthreads();
  float* dst = out + (size_t)b * NN * CC;
#pragma unroll
  for (int i = 0; i < 32; i += 8)
    dst[(size_t)(n0 + ty + i) * CC + c0 + tx] = tile[tx][ty + i];
}

// ---------------------------------------------------------------- FPS
__device__ __forceinline__ void vimax_step(float& v, int& i, float v2, int i2) {
  if (v2 > v || (v2 == v && i2 < i)) { v = v2; i = i2; }
}

__global__ __launch_bounds__(1024) void k_fps(const float* __restrict__ pc, int* __restrict__ fps_idx) {
  const int b = blockIdx.x, tid = threadIdx.x;
  const float* pb = pc + (size_t)b * 3 * NN;
  float px[8], py[8], pz[8], dist[8];
#pragma unroll
  for (int j = 0; j < 8; ++j) {
    int i = tid * 8 + j;
    px[j] = pb[i]; py[j] = pb[NN + i]; pz[j] = pb[2 * NN + i];
    dist[j] = 1e10f;
  }
  __shared__ u64 wk[2][16];
  __shared__ float cs[2][3];
  const int lane = tid & 63, wid = tid >> 6;
  if (tid == 0) { cs[0][0] = px[0]; cs[0][1] = py[0]; cs[0][2] = pz[0]; }
  int farthest = 0;
  for (int k = 0; k < SS; ++k) {
    __syncthreads();  // alpha: cs[p] visible
    const int p = k & 1;
    if (tid == 0) fps_idx[b * SS + k] = farthest;
    const float cx = cs[p][0], cy = cs[p][1], cz = cs[p][2];
    float bv = -1.0f; int bi = 0;
    {
#pragma clang fp contract(off)
#pragma unroll
      for (int j = 0; j < 8; ++j) {
        float dx = px[j] - cx, dy = py[j] - cy, dz = pz[j] - cz;
        float d = sqrtf((dx * dx + dy * dy) + dz * dz);
        float nd = fminf(dist[j], d);
        dist[j] = nd;
        if (nd > bv) { bv = nd; bi = tid * 8 + j; }
      }
    }
    // wave allreduce argmax (tie -> smallest index). row_ror 1,2,4,8 then xor16/xor32.
#define DPPSTEP(CTL) { \
      float v2 = __int_as_float(__builtin_amdgcn_update_dpp(0, __float_as_int(bv), CTL, 0xf, 0xf, false)); \
      int   i2 = __builtin_amdgcn_update_dpp(0, bi, CTL, 0xf, 0xf, false); \
      vimax_step(bv, bi, v2, i2); }
    DPPSTEP(0x121) DPPSTEP(0x122) DPPSTEP(0x124) DPPSTEP(0x128)
#undef DPPSTEP
    { float v2 = __shfl_xor(bv, 16, 64); int i2 = __shfl_xor(bi, 16, 64); vimax_step(bv, bi, v2, i2); }
    { float v2 = __shfl_xor(bv, 32, 64); int i2 = __shfl_xor(bi, 32, 64); vimax_step(bv, bi, v2, i2); }
    if (lane == 0)
      wk[p][wid] = ((u64)__float_as_uint(bv) << 32) | (u64)(0xFFFFFFFFu - (u32)bi);
    __syncthreads();  // beta: wk visible
    u64 key = wk[p][lane & 15];
#define DPPSTEP64(CTL) { \
      u32 lo = (u32)key, hi = (u32)(key >> 32); \
      u32 lo2 = (u32)__builtin_amdgcn_update_dpp(0, (int)lo, CTL, 0xf, 0xf, false); \
      u32 hi2 = (u32)__builtin_amdgcn_update_dpp(0, (int)hi, CTL, 0xf, 0xf, false); \
      u64 k2 = ((u64)hi2 << 32) | (u64)lo2; if (k2 > key) key = k2; }
    DPPSTEP64(0x121) DPPSTEP64(0x122) DPPSTEP64(0x124) DPPSTEP64(0x128)
#undef DPPSTEP64
    farthest = (int)(0xFFFFFFFFu - (u32)(key & 0xFFFFFFFFull));
    if ((farthest >> 3) == tid) {
      int j = farthest & 7, pn = (k + 1) & 1;
      cs[pn][0] = px[j]; cs[pn][1] = py[j]; cs[pn][2] = pz[j];
    }
  }
}

// ---------------------------------------------------------------- gather new_coor + out0
__global__ void k_gather(const float* __restrict__ pc, const int* __restrict__ fps_idx,
                         float* __restrict__ ncoor, float* __restrict__ out0) {
  int t = blockIdx.x * 256 + threadIdx.x;
  if (t >= BB * SS) return;
  int b = t / SS, s = t % SS;
  int id = fps_idx[t];
  const float* base = pc + (size_t)b * 3 * NN;
  float x = base[id], y = base[NN + id], z = base[2 * NN + id];
  ncoor[(size_t)t * 3] = x; ncoor[(size_t)t * 3 + 1] = y; ncoor[(size_t)t * 3 + 2] = z;
  size_t o = (size_t)b * 3 * SS + s;
  out0[o] = x; out0[o + SS] = y; out0[o + 2 * SS] = z;
}

// ---------------------------------------------------------------- kNN (k=32 within radius, fill with argmin)
// Distance replicates np's _sqdist bit-for-bit:
//   dot: np.einsum inner sum-of-products loop -> gcc -ffp-contract=fast -> FMA chain
//        acc = fma(a2,b2, fma(a1,b1, a0*b0))
//   norms: np.sum(x**2,-1) over a MATERIALIZED squares array -> pure sequential adds (no FMA)
//   d = ((-2*dot) + ||q||^2) + ||p||^2  (sequential adds, f32 throughout)
__global__ __launch_bounds__(256) void k_knn(const float* __restrict__ candp,
                                             const float* __restrict__ newc,
                                             int mode, int ncand, float r2,
                                             int* __restrict__ gidx) {
  __shared__ float cd[2048];
  __shared__ int ci[2048];
  __shared__ int hist[64];
  __shared__ int cnt, oc, binT, mlow;
  const int q = blockIdx.x, tid = threadIdx.x;
  const int b = q / SS;
  if (tid == 0) { cnt = 0; oc = 0; }
  if (tid < 64) hist[tid] = 0;
  __syncthreads();
  const float qx = newc[(size_t)q * 3], qy = newc[(size_t)q * 3 + 1], qz = newc[(size_t)q * 3 + 2];
  float qn;
  {
#pragma clang fp contract(off)
    qn = (qx * qx + qy * qy) + qz * qz;
  }
  const float sc = 64.0f / r2;
  const float* base = (mode == 0) ? candp + (size_t)b * 3 * NN : candp + (size_t)b * SS * 3;
  for (int i = tid; i < ncand; i += 256) {
    float x, y, z;
    if (mode == 0) { x = base[i]; y = base[NN + i]; z = base[2 * NN + i]; }
    else { x = base[3 * i]; y = base[3 * i + 1]; z = base[3 * i + 2]; }
    // FMA-chain dot (np einsum), contract-off norms (np materialized squares)
    float dot = fmaf(qz, z, fmaf(qy, y, qx * x));
    float d;
    {
#pragma clang fp contract(off)
      float pn = (x * x + y * y) + z * z;
      d = ((-2.0f * dot) + qn) + pn;
    }
    if (d <= r2) {
      int pp = atomicAdd(&cnt, 1);
      if (pp < 2048) { cd[pp] = d; ci[pp] = i; }
      float db = (d > 0.0f) ? d : 0.0f;
      atomicAdd(&hist[min(63, (int)(db * sc))], 1);
    }
  }
  __syncthreads();
  const int M = min(cnt, 2048);
  if (tid == 0) {
    if (M > 32) {
      int c = 0, t = 0;
      for (t = 0; t < 64; ++t) { if (c + hist[t] >= 32) break; c += hist[t]; }
      binT = t; mlow = c;
    } else binT = -1;
  }
  __syncthreads();
  int* out = gidx + (size_t)q * 32;
  if (binT < 0) {
    for (int j = tid; j < M; j += 256) out[atomicAdd(&oc, 1)] = ci[j];
    __syncthreads();
    if (tid == 0 && M < 32) {
      float bd = 1e30f; int bx = 0x7FFFFFFF;
      for (int j = 0; j < M; ++j)
        if (cd[j] < bd || (cd[j] == bd && ci[j] < bx)) { bd = cd[j]; bx = ci[j]; }
      for (int j = M; j < 32; ++j) out[j] = bx;
    }
  } else {
    const int bt = binT, m = mlow;
    for (int j = tid; j < M; j += 256) {
      float dbj = (cd[j] > 0.0f) ? cd[j] : 0.0f;
      int bin = min(63, (int)(dbj * sc));
      if (bin < bt) out[atomicAdd(&oc, 1)] = ci[j];
      else if (bin == bt) {
        int r = 0; const float dj = cd[j]; const int ij = ci[j];
        for (int kk = 0; kk < M; ++kk) {
          float dbk = (cd[kk] > 0.0f) ? cd[kk] : 0.0f;
          if (min(63, (int)(dbk * sc)) == bt &&
              (cd[kk] < dj || (cd[kk] == dj && ci[kk] < ij))) ++r;
        }
        if (m + r < 32) out[m + r] = ci[j];
      }
    }
  }
}

// ---------------------------------------------------------------- grouped MLP + max  (out 128 ch)
template <int FDIM>
__global__ __launch_bounds__(256) void k_group_mlp(
    const float* __restrict__ fea, const int* __restrict__ gidx,
    const float* __restrict__ newc, const float* __restrict__ candp,
    int mode, int ncand, float radius,
    const float* __restrict__ wp, float* __restrict__ outf) {
  constexpr int CP4 = FDIM + 4;     // padded cols (67->68, 131->132)
  constexpr int NC4 = CP4 / 4;
  __shared__ float4 g4[2][32][NC4];
  __shared__ int sidx[2][32];
  __shared__ float sq[2][3];
  __shared__ float pf[2][4][128];
  const int tid = threadIdx.x;
  const int rs = tid >> 7, tl = tid & 127;
  const int dt = tl & 31, et = tl >> 5;
  const int d0 = dt * 4, e0 = et * 8;
  const int row0 = blockIdx.x * 16;
  for (int rp = 0; rp < 16; rp += 2) {
    const int row = row0 + rp + rs;
    if (tl < 32) sidx[rs][tl] = gidx[(size_t)row * 32 + tl];
    if (tl < 3) sq[rs][tl] = newc[(size_t)row * 3 + tl];
    __syncthreads();
    const int bb2 = row / SS;
    const float* fb = fea + (size_t)bb2 * ncand * FDIM;
    const float* cb = (mode == 0) ? candp + (size_t)bb2 * 3 * NN
                                  : candp + (size_t)bb2 * SS * 3;
    float* gf = (float*)&g4[rs][0][0];
    for (int qq = tl; qq < 32 * CP4; qq += 128) {
      int e = qq / CP4, c = qq - e * CP4;
      int id = sidx[rs][e];
      float v;
      if (c < FDIM) v = fb[(size_t)id * FDIM + c];
      else if (c < FDIM + 3) {
        int comp = c - FDIM;
        float pcv = (mode == 0) ? cb[(size_t)comp * NN + id] : cb[(size_t)id * 3 + comp];
        v = (pcv - sq[rs][comp]) / radius;
      } else v = 0.0f;
      gf[qq] = v;
    }
    __syncthreads();
    float acc[4][8];
#pragma unroll
    for (int i = 0; i < 4; ++i)
#pragma unroll
      for (int j = 0; j < 8; ++j) acc[i][j] = 0.0f;
    const float4* w4 = (const float4*)wp;
    for (int c4 = 0; c4 < NC4; ++c4) {
      float4 wv[4], gv[8];
#pragma unroll
      for (int i = 0; i < 4; ++i) wv[i] = w4[(size_t)(d0 + i) * NC4 + c4];
#pragma unroll
      for (int j = 0; j < 8; ++j) gv[j] = g4[rs][e0 + j][c4];
#pragma unroll
      for (int i = 0; i < 4; ++i)
#pragma unroll
        for (int j = 0; j < 8; ++j) {
          acc[i][j] += wv[i].x * gv[j].x;
          acc[i][j] += wv[i].y * gv[j].y;
          acc[i][j] += wv[i].z * gv[j].z;
          acc[i][j] += wv[i].w * gv[j].w;
        }
    }
#pragma unroll
    for (int i = 0; i < 4; ++i) {
      float m = acc[i][0];
#pragma unroll
      for (int j = 1; j < 8; ++j) m = fmaxf(m, acc[i][j]);
      pf[rs][et][d0 + i] = m;
    }
    __syncthreads();
    {
      const int d = tid & 127, r2s = tid >> 7;
      const int rowW = row0 + rp + r2s;
      float m = fmaxf(fmaxf(pf[r2s][0][d], pf[r2s][1][d]),
                      fmaxf(pf[r2s][2][d], pf[r2s][3][d]));
      outf[(size_t)rowW * 128 + d] = fmaxf(m, 0.0f);
    }
    __syncthreads();
  }
}

// ---------------------------------------------------------------- dense GEMM: Out = relu(A(M,K) * W(N,K)^T [+ Id])
template <bool RESID>
__global__ __launch_bounds__(256) void k_dense(
    const float* __restrict__ A, const float* __restrict__ W,
    const float* __restrict__ Id, float* __restrict__ Out,
    int K, int Ntot) {
  __shared__ float4 sa[64][17], sb[64][17];
  const int m0 = blockIdx.x * 64, n0 = blockIdx.y * 64;
  const int tid = threadIdx.x;
  const int mt = tid & 15, nt = tid >> 4;
  float acc[4][4];
#pragma unroll
  for (int i = 0; i < 4; ++i)
#pragma unroll
    for (int j = 0; j < 4; ++j) acc[i][j] = 0.0f;
  for (int kc = 0; kc < K; kc += 64) {
    for (int q2 = tid; q2 < 2048; q2 += 256) {
      int half = q2 >> 10, qq = q2 & 1023;
      int r = qq >> 4, c = qq & 15;
      const float* src = half ? (W + (size_t)(n0 + r) * K + kc + c * 4)
                              : (A + (size_t)(m0 + r) * K + kc + c * 4);
      float4 v = *(const float4*)src;
      if (half) sb[r][c] = v; else sa[r][c] = v;
    }
    __syncthreads();
#pragma unroll
    for (int c = 0; c < 16; ++c) {
      const int ks = (c + mt + nt) & 15;  // swizzle to break LDS bank conflicts
      float4 av[4], bv[4];
#pragma unroll
      for (int i = 0; i < 4; ++i) av[i] = sa[mt * 4 + i][ks];
#pragma unroll
      for (int j = 0; j < 4; ++j) bv[j] = sb[nt * 4 + j][ks];
#pragma unroll
      for (int i = 0; i < 4; ++i)
#pragma unroll
        for (int j = 0; j < 4; ++j) {
          acc[i][j] += av[i].x * bv[j].x;
          acc[i][j] += av[i].y * bv[j].y;
          acc[i][j] += av[i].z * bv[j].z;
          acc[i][j] += av[i].w * bv[j].w;
        }
    }
    __syncthreads();
  }
#pragma unroll
  for (int i = 0; i < 4; ++i)
#pragma unroll
    for (int j = 0; j < 4; ++j) {
      size_t o = (size_t)(m0 + mt * 4 + i) * Ntot + n0 + nt * 4 + j;
      float v = acc[i][j];
      if (RESID) v += Id[o];
      Out[o] = fmaxf(v, 0.0f);
    }
}

// ---------------------------------------------------------------- pad weights rows to 4-aligned cols
__global__ void k_pad_w(const float* __restrict__ src, float* __restrict__ dst,
                        int rows, int cin, int cp4) {
  int t = blockIdx.x * 256 + threadIdx.x;
  if (t >= rows * cp4) return;
  int r = t / cp4, c = t - r * cp4;
  dst[t] = (c < cin) ? src[(size_t)r * cin + c] : 0.0f;
}

// ---------------------------------------------------------------- out1 transpose (B*S,128) -> (B,128,S)
__global__ void k_out1_t(const float* __restrict__ in, float* __restrict__ out) {
  __shared__ float tile[32][33];
  const int b = blockIdx.z;
  const int s0 = blockIdx.x * 32, d0 = blockIdx.y * 32;
  const int tx = threadIdx.x, ty = threadIdx.y;
#pragma unroll
  for (int i = 0; i < 32; i += 8)
    tile[ty + i][tx] = in[(size_t)(b * SS + s0 + ty + i) * 128 + d0 + tx];
  __syncthreads();
#pragma unroll
  for (int i = 0; i < 32; i += 8)
    out[(size_t)(b * 128 + d0 + ty + i) * SS + s0 + tx] = tile[tx][ty + i];
}

// ----------------------------------------------------------------
extern "C" void kernel_launch(void* const* d_in, const int* in_sizes, int n_in,
                              void* d_out, int out_size, void* d_ws, size_t ws_size,
                              hipStream_t stream) {
  const float* pc    = (const float*)d_in[0];
  const float* pfea  = (const float*)d_in[1];
  const float* w_sa  = (const float*)d_in[2];
  const float* w_la1 = (const float*)d_in[3];
  const float* w1_1  = (const float*)d_in[4];
  const float* w2_1  = (const float*)d_in[5];
  const float* w_la2 = (const float*)d_in[6];
  const float* w1_2  = (const float*)d_in[7];
  const float* w2_2  = (const float*)d_in[8];
  float* out0 = (float*)d_out;
  float* out1 = out0 + (size_t)BB * 3 * SS;

  char* wsp = (char*)d_ws;
  size_t off = 0;
  auto alloc = [&](size_t bytes) -> void* {
    void* p = wsp + off;
    off = (off + bytes + 255) & ~(size_t)255;
    return p;
  };
  float* hbuf = (float*)alloc((size_t)BB * SS * HHV * 4);  // 16 MB; also aliased as feaT (disjoint in time)
  float* feaT = hbuf;                                      // 8 MB needed, used only before hbuf
  int*   fpsi = (int*)alloc((size_t)BB * SS * 4);
  float* ncoor = (float*)alloc((size_t)BB * SS * 3 * 4);
  int*   gi = (int*)alloc((size_t)BB * SS * GG * 4);
  float* fa = (float*)alloc((size_t)BB * SS * C2V * 4);
  float* fb = (float*)alloc((size_t)BB * SS * C2V * 4);
  float* wsap = (float*)alloc(128 * 68 * 4);
  float* wla1p = (float*)alloc(128 * 132 * 4);
  float* wla2p = (float*)alloc(128 * 132 * 4);

  k_pad_w<<<dim3((128 * 68 + 255) / 256), dim3(256), 0, stream>>>(w_sa, wsap, 128, 67, 68);
  k_pad_w<<<dim3((128 * 132 + 255) / 256), dim3(256), 0, stream>>>(w_la1, wla1p, 128, 131, 132);
  k_pad_w<<<dim3((128 * 132 + 255) / 256), dim3(256), 0, stream>>>(w_la2, wla2p, 128, 131, 132);

  k_transpose_fea<<<dim3(NN / 32, CC / 32, BB), dim3(32, 8), 0, stream>>>(pfea, feaT);
  k_fps<<<dim3(BB), dim3(1024), 0, stream>>>(pc, fpsi);
  k_gather<<<dim3((BB * SS + 255) / 256), dim3(256), 0, stream>>>(pc, fpsi, ncoor, out0);

  // stage 1: group among original N points, r=0.2
  k_knn<<<dim3(BB * SS), dim3(256), 0, stream>>>(pc, ncoor, 0, NN, 0.04f, gi);
  k_group_mlp<64><<<dim3(BB * SS / 16), dim3(256), 0, stream>>>(feaT, gi, ncoor, pc, 0, NN, 0.2f, wsap, fa);

  // shared grouping for both inv-res blocks (same points, same radius 0.4)
  k_knn<<<dim3(BB * SS), dim3(256), 0, stream>>>(ncoor, ncoor, 1, SS, 0.16f, gi);

  // inv-res block 1
  k_group_mlp<128><<<dim3(BB * SS / 16), dim3(256), 0, stream>>>(fa, gi, ncoor, ncoor, 1, SS, 0.4f, wla1p, fb);
  k_dense<false><<<dim3(128, 8), dim3(256), 0, stream>>>(fb, w1_1, nullptr, hbuf, 128, 512);
  k_dense<true><<<dim3(128, 2), dim3(256), 0, stream>>>(hbuf, w2_1, fa, fb, 512, 128);

  // inv-res block 2
  k_group_mlp<128><<<dim3(BB * SS / 16), dim3(256), 0, stream>>>(fb, gi, ncoor, ncoor, 1, SS, 0.4f, wla2p, fa);
  k_dense<false><<<dim3(128, 8), dim3(256), 0, stream>>>(fa, w1_2, nullptr, hbuf, 128, 512);
  k_dense<true><<<dim3(128, 2), dim3(256), 0, stream>>>(hbuf, w2_2, fb, fa, 512, 128);

  k_out1_t<<<dim3(SS / 32, 128 / 32, BB), dim3(32, 8), 0, stream>>>(fa, out1);
}

// Round 6
// 5300.546 us; speedup vs baseline: 1.1058x; 1.1058x over previous
//
#include <hip/hip_runtime.h>
#include <hip/hip_bf16.h>

#define BB 4
#define NN 8192
#define CC 64
#define SS 2048
#define GG 32
#define C2V 128
#define HHV 512

typedef unsigned long long u64;
typedef unsigned int u32;

// ---------------------------------------------------------------- transpose fea (B,C,N)->(B,N,C)
__global__ void k_transpose_fea(const float* __restrict__ in, float* __restrict__ out) {
  __shared__ float tile[32][33];
  const int b = blockIdx.z;
  const int n0 = blockIdx.x * 32, c0 = blockIdx.y * 32;
  const int tx = threadIdx.x, ty = threadIdx.y;
  const float* src = in + (size_t)b * CC * NN;
#pragma unroll
  for (int i = 0; i < 32; i += 8)
    tile[ty + i][tx] = src[(size_t)(c0 + ty + i) * NN + n0 + tx];
  __syncthreads();
  float* dst = out + (size_t)b * NN * CC;
#pragma unroll
  for (int i = 0; i < 32; i += 8)
    dst[(size_t)(n0 + ty + i) * CC + c0 + tx] = tile[tx][ty + i];
}

// ---------------------------------------------------------------- FPS (v2)
// 512 threads = 8 waves, 16 pts/lane, ALL arrays compile-time indexed (VGPR-resident).
// One barrier per step: publish per-wave winner key (u64 = distbits<<32 | ~idx) to
// double-buffered LDS; next step reduces 8 keys via DPP row_ror, re-reads winner
// coords from global (uniform broadcast, L2-hot). Math identical to the verified
// round-5 semantics: contract-off, sqrtf, fminf, strict-> ascending-index argmax.
__global__ __launch_bounds__(512) void k_fps(const float* __restrict__ pc, int* __restrict__ fps_idx) {
  const int b = blockIdx.x, tid = threadIdx.x;
  const int lane = tid & 63, wid = tid >> 6;
  const float* pb = pc + (size_t)b * 3 * NN;
  float px[16], py[16], pz[16], dist[16];
  const float4* p4x = (const float4*)pb;
  const float4* p4y = (const float4*)(pb + NN);
  const float4* p4z = (const float4*)(pb + 2 * NN);
#pragma unroll
  for (int q = 0; q < 4; ++q) {
    float4 vx = p4x[tid * 4 + q], vy = p4y[tid * 4 + q], vz = p4z[tid * 4 + q];
    px[q * 4 + 0] = vx.x; px[q * 4 + 1] = vx.y; px[q * 4 + 2] = vx.z; px[q * 4 + 3] = vx.w;
    py[q * 4 + 0] = vy.x; py[q * 4 + 1] = vy.y; py[q * 4 + 2] = vy.z; py[q * 4 + 3] = vy.w;
    pz[q * 4 + 0] = vz.x; pz[q * 4 + 1] = vz.y; pz[q * 4 + 2] = vz.z; pz[q * 4 + 3] = vz.w;
    dist[q * 4 + 0] = 1e10f; dist[q * 4 + 1] = 1e10f; dist[q * 4 + 2] = 1e10f; dist[q * 4 + 3] = 1e10f;
  }
  __shared__ u64 sK[2][8];
  // prologue: step-0 winner is index 0 (key hi = 0xFFFFFFFF beats any dist bits)
  if (lane == 0)
    sK[0][wid] = (wid == 0) ? ((((u64)0xFFFFFFFFu) << 32) | (u64)0xFFFFFFFFu) : 0ull;
  __syncthreads();

#define DPPK64(K, CTL) { \
      u32 lo = (u32)(K), hi = (u32)((K) >> 32); \
      u32 lo2 = (u32)__builtin_amdgcn_update_dpp(0, (int)lo, CTL, 0xf, 0xf, false); \
      u32 hi2 = (u32)__builtin_amdgcn_update_dpp(0, (int)hi, CTL, 0xf, 0xf, false); \
      u64 k2 = ((u64)hi2 << 32) | (u64)lo2; if (k2 > (K)) (K) = k2; }

  for (int k = 0; k < SS; ++k) {
    const int p = k & 1;
    // ---- cross-wave reduce of the 8 published keys (slots repeat every 8 lanes;
    //      row_ror windows of 1,2,4 cover all 8 distinct slots for every lane)
    u64 kk = sK[p][lane & 7];
    DPPK64(kk, 0x121) DPPK64(kk, 0x122) DPPK64(kk, 0x124)
    const int g = (int)(0xFFFFFFFFu - (u32)kk);
    if (tid == 0) fps_idx[b * SS + k] = g;
    // winner coords: uniform broadcast load (L2-hot)
    const float cx = pb[g], cy = pb[NN + g], cz = pb[2 * NN + g];
    // ---- distance update + local argmax (all register-resident, compile-time idx)
    float bv = -1.0f; u32 bienc = 0;
    {
#pragma clang fp contract(off)
#pragma unroll
      for (int j = 0; j < 16; ++j) {
        float dx = px[j] - cx, dy = py[j] - cy, dz = pz[j] - cz;
        float d = sqrtf((dx * dx + dy * dy) + dz * dz);
        float nd = fminf(dist[j], d);
        dist[j] = nd;
        if (nd > bv) { bv = nd; bienc = (u32)(tid * 16 + j); }
      }
    }
    // ---- in-wave allreduce on u64 key (row_ror butterfly + xor16/xor32)
    u64 key = (((u64)__float_as_uint(bv)) << 32) | (u64)(0xFFFFFFFFu - bienc);
    DPPK64(key, 0x121) DPPK64(key, 0x122) DPPK64(key, 0x124) DPPK64(key, 0x128)
    { u64 k2 = __shfl_xor(key, 16, 64); if (k2 > key) key = k2; }
    { u64 k2 = __shfl_xor(key, 32, 64); if (k2 > key) key = k2; }
    if (lane == 0) sK[p ^ 1][wid] = key;
    __syncthreads();  // single barrier per step (double-buffered keys)
  }
#undef DPPK64
}

// ---------------------------------------------------------------- gather new_coor + out0
__global__ void k_gather(const float* __restrict__ pc, const int* __restrict__ fps_idx,
                         float* __restrict__ ncoor, float* __restrict__ out0) {
  int t = blockIdx.x * 256 + threadIdx.x;
  if (t >= BB * SS) return;
  int b = t / SS, s = t % SS;
  int id = fps_idx[t];
  const float* base = pc + (size_t)b * 3 * NN;
  float x = base[id], y = base[NN + id], z = base[2 * NN + id];
  ncoor[(size_t)t * 3] = x; ncoor[(size_t)t * 3 + 1] = y; ncoor[(size_t)t * 3 + 2] = z;
  size_t o = (size_t)b * 3 * SS + s;
  out0[o] = x; out0[o + SS] = y; out0[o + 2 * SS] = z;
}

// ---------------------------------------------------------------- kNN (k=32 within radius, fill with argmin)
// Distance replicates np's _sqdist bit-for-bit:
//   dot: np.einsum inner sum-of-products loop -> gcc -ffp-contract=fast -> FMA chain
//        acc = fma(a2,b2, fma(a1,b1, a0*b0))
//   norms: np.sum(x**2,-1) over a MATERIALIZED squares array -> pure sequential adds (no FMA)
//   d = ((-2*dot) + ||q||^2) + ||p||^2  (sequential adds, f32 throughout)
__global__ __launch_bounds__(256) void k_knn(const float* __restrict__ candp,
                                             const float* __restrict__ newc,
                                             int mode, int ncand, float r2,
                                             int* __restrict__ gidx) {
  __shared__ float cd[2048];
  __shared__ int ci[2048];
  __shared__ int hist[64];
  __shared__ int cnt, oc, binT, mlow;
  const int q = blockIdx.x, tid = threadIdx.x;
  const int b = q / SS;
  if (tid == 0) { cnt = 0; oc = 0; }
  if (tid < 64) hist[tid] = 0;
  __syncthreads();
  const float qx = newc[(size_t)q * 3], qy = newc[(size_t)q * 3 + 1], qz = newc[(size_t)q * 3 + 2];
  float qn;
  {
#pragma clang fp contract(off)
    qn = (qx * qx + qy * qy) + qz * qz;
  }
  const float sc = 64.0f / r2;
  const float* base = (mode == 0) ? candp + (size_t)b * 3 * NN : candp + (size_t)b * SS * 3;
  for (int i = tid; i < ncand; i += 256) {
    float x, y, z;
    if (mode == 0) { x = base[i]; y = base[NN + i]; z = base[2 * NN + i]; }
    else { x = base[3 * i]; y = base[3 * i + 1]; z = base[3 * i + 2]; }
    // FMA-chain dot (np einsum), contract-off norms (np materialized squares)
    float dot = fmaf(qz, z, fmaf(qy, y, qx * x));
    float d;
    {
#pragma clang fp contract(off)
      float pn = (x * x + y * y) + z * z;
      d = ((-2.0f * dot) + qn) + pn;
    }
    if (d <= r2) {
      int pp = atomicAdd(&cnt, 1);
      if (pp < 2048) { cd[pp] = d; ci[pp] = i; }
      float db = (d > 0.0f) ? d : 0.0f;
      atomicAdd(&hist[min(63, (int)(db * sc))], 1);
    }
  }
  __syncthreads();
  const int M = min(cnt, 2048);
  if (tid == 0) {
    if (M > 32) {
      int c = 0, t = 0;
      for (t = 0; t < 64; ++t) { if (c + hist[t] >= 32) break; c += hist[t]; }
      binT = t; mlow = c;
    } else binT = -1;
  }
  __syncthreads();
  int* out = gidx + (size_t)q * 32;
  if (binT < 0) {
    for (int j = tid; j < M; j += 256) out[atomicAdd(&oc, 1)] = ci[j];
    __syncthreads();
    if (tid == 0 && M < 32) {
      float bd = 1e30f; int bx = 0x7FFFFFFF;
      for (int j = 0; j < M; ++j)
        if (cd[j] < bd || (cd[j] == bd && ci[j] < bx)) { bd = cd[j]; bx = ci[j]; }
      for (int j = M; j < 32; ++j) out[j] = bx;
    }
  } else {
    const int bt = binT, m = mlow;
    for (int j = tid; j < M; j += 256) {
      float dbj = (cd[j] > 0.0f) ? cd[j] : 0.0f;
      int bin = min(63, (int)(dbj * sc));
      if (bin < bt) out[atomicAdd(&oc, 1)] = ci[j];
      else if (bin == bt) {
        int r = 0; const float dj = cd[j]; const int ij = ci[j];
        for (int kk = 0; kk < M; ++kk) {
          float dbk = (cd[kk] > 0.0f) ? cd[kk] : 0.0f;
          if (min(63, (int)(dbk * sc)) == bt &&
              (cd[kk] < dj || (cd[kk] == dj && ci[kk] < ij))) ++r;
        }
        if (m + r < 32) out[m + r] = ci[j];
      }
    }
  }
}

// ---------------------------------------------------------------- grouped MLP + max  (out 128 ch)
template <int FDIM>
__global__ __launch_bounds__(256) void k_group_mlp(
    const float* __restrict__ fea, const int* __restrict__ gidx,
    const float* __restrict__ newc, const float* __restrict__ candp,
    int mode, int ncand, float radius,
    const float* __restrict__ wp, float* __restrict__ outf) {
  constexpr int CP4 = FDIM + 4;     // padded cols (67->68, 131->132)
  constexpr int NC4 = CP4 / 4;
  __shared__ float4 g4[2][32][NC4];
  __shared__ int sidx[2][32];
  __shared__ float sq[2][3];
  __shared__ float pf[2][4][128];
  const int tid = threadIdx.x;
  const int rs = tid >> 7, tl = tid & 127;
  const int dt = tl & 31, et = tl >> 5;
  const int d0 = dt * 4, e0 = et * 8;
  const int row0 = blockIdx.x * 16;
  for (int rp = 0; rp < 16; rp += 2) {
    const int row = row0 + rp + rs;
    if (tl < 32) sidx[rs][tl] = gidx[(size_t)row * 32 + tl];
    if (tl < 3) sq[rs][tl] = newc[(size_t)row * 3 + tl];
    __syncthreads();
    const int bb2 = row / SS;
    const float* fb = fea + (size_t)bb2 * ncand * FDIM;
    const float* cb = (mode == 0) ? candp + (size_t)bb2 * 3 * NN
                                  : candp + (size_t)bb2 * SS * 3;
    float* gf = (float*)&g4[rs][0][0];
    for (int qq = tl; qq < 32 * CP4; qq += 128) {
      int e = qq / CP4, c = qq - e * CP4;
      int id = sidx[rs][e];
      float v;
      if (c < FDIM) v = fb[(size_t)id * FDIM + c];
      else if (c < FDIM + 3) {
        int comp = c - FDIM;
        float pcv = (mode == 0) ? cb[(size_t)comp * NN + id] : cb[(size_t)id * 3 + comp];
        v = (pcv - sq[rs][comp]) / radius;
      } else v = 0.0f;
      gf[qq] = v;
    }
    __syncthreads();
    float acc[4][8];
#pragma unroll
    for (int i = 0; i < 4; ++i)
#pragma unroll
      for (int j = 0; j < 8; ++j) acc[i][j] = 0.0f;
    const float4* w4 = (const float4*)wp;
    for (int c4 = 0; c4 < NC4; ++c4) {
      float4 wv[4], gv[8];
#pragma unroll
      for (int i = 0; i < 4; ++i) wv[i] = w4[(size_t)(d0 + i) * NC4 + c4];
#pragma unroll
      for (int j = 0; j < 8; ++j) gv[j] = g4[rs][e0 + j][c4];
#pragma unroll
      for (int i = 0; i < 4; ++i)
#pragma unroll
        for (int j = 0; j < 8; ++j) {
          acc[i][j] += wv[i].x * gv[j].x;
          acc[i][j] += wv[i].y * gv[j].y;
          acc[i][j] += wv[i].z * gv[j].z;
          acc[i][j] += wv[i].w * gv[j].w;
        }
    }
#pragma unroll
    for (int i = 0; i < 4; ++i) {
      float m = acc[i][0];
#pragma unroll
      for (int j = 1; j < 8; ++j) m = fmaxf(m, acc[i][j]);
      pf[rs][et][d0 + i] = m;
    }
    __syncthreads();
    {
      const int d = tid & 127, r2s = tid >> 7;
      const int rowW = row0 + rp + r2s;
      float m = fmaxf(fmaxf(pf[r2s][0][d], pf[r2s][1][d]),
                      fmaxf(pf[r2s][2][d], pf[r2s][3][d]));
      outf[(size_t)rowW * 128 + d] = fmaxf(m, 0.0f);
    }
    __syncthreads();
  }
}

// ---------------------------------------------------------------- dense GEMM: Out = relu(A(M,K) * W(N,K)^T [+ Id])
template <bool RESID>
__global__ __launch_bounds__(256) void k_dense(
    const float* __restrict__ A, const float* __restrict__ W,
    const float* __restrict__ Id, float* __restrict__ Out,
    int K, int Ntot) {
  __shared__ float4 sa[64][17], sb[64][17];
  const int m0 = blockIdx.x * 64, n0 = blockIdx.y * 64;
  const int tid = threadIdx.x;
  const int mt = tid & 15, nt = tid >> 4;
  float acc[4][4];
#pragma unroll
  for (int i = 0; i < 4; ++i)
#pragma unroll
    for (int j = 0; j < 4; ++j) acc[i][j] = 0.0f;
  for (int kc = 0; kc < K; kc += 64) {
    for (int q2 = tid; q2 < 2048; q2 += 256) {
      int half = q2 >> 10, qq = q2 & 1023;
      int r = qq >> 4, c = qq & 15;
      const float* src = half ? (W + (size_t)(n0 + r) * K + kc + c * 4)
                              : (A + (size_t)(m0 + r) * K + kc + c * 4);
      float4 v = *(const float4*)src;
      if (half) sb[r][c] = v; else sa[r][c] = v;
    }
    __syncthreads();
#pragma unroll
    for (int c = 0; c < 16; ++c) {
      const int ks = (c + mt + nt) & 15;  // swizzle to break LDS bank conflicts
      float4 av[4], bv[4];
#pragma unroll
      for (int i = 0; i < 4; ++i) av[i] = sa[mt * 4 + i][ks];
#pragma unroll
      for (int j = 0; j < 4; ++j) bv[j] = sb[nt * 4 + j][ks];
#pragma unroll
      for (int i = 0; i < 4; ++i)
#pragma unroll
        for (int j = 0; j < 4; ++j) {
          acc[i][j] += av[i].x * bv[j].x;
          acc[i][j] += av[i].y * bv[j].y;
          acc[i][j] += av[i].z * bv[j].z;
          acc[i][j] += av[i].w * bv[j].w;
        }
    }
    __syncthreads();
  }
#pragma unroll
  for (int i = 0; i < 4; ++i)
#pragma unroll
    for (int j = 0; j < 4; ++j) {
      size_t o = (size_t)(m0 + mt * 4 + i) * Ntot + n0 + nt * 4 + j;
      float v = acc[i][j];
      if (RESID) v += Id[o];
      Out[o] = fmaxf(v, 0.0f);
    }
}

// ---------------------------------------------------------------- pad weights rows to 4-aligned cols
__global__ void k_pad_w(const float* __restrict__ src, float* __restrict__ dst,
                        int rows, int cin, int cp4) {
  int t = blockIdx.x * 256 + threadIdx.x;
  if (t >= rows * cp4) return;
  int r = t / cp4, c = t - r * cp4;
  dst[t] = (c < cin) ? src[(size_t)r * cin + c] : 0.0f;
}

// ---------------------------------------------------------------- out1 transpose (B*S,128) -> (B,128,S)
__global__ void k_out1_t(const float* __restrict__ in, float* __restrict__ out) {
  __shared__ float tile[32][33];
  const int b = blockIdx.z;
  const int s0 = blockIdx.x * 32, d0 = blockIdx.y * 32;
  const int tx = threadIdx.x, ty = threadIdx.y;
#pragma unroll
  for (int i = 0; i < 32; i += 8)
    tile[ty + i][tx] = in[(size_t)(b * SS + s0 + ty + i) * 128 + d0 + tx];
  __syncthreads();
#pragma unroll
  for (int i = 0; i < 32; i += 8)
    out[(size_t)(b * 128 + d0 + ty + i) * SS + s0 + tx] = tile[tx][ty + i];
}

// ----------------------------------------------------------------
extern "C" void kernel_launch(void* const* d_in, const int* in_sizes, int n_in,
                              void* d_out, int out_size, void* d_ws, size_t ws_size,
                              hipStream_t stream) {
  const float* pc    = (const float*)d_in[0];
  const float* pfea  = (const float*)d_in[1];
  const float* w_sa  = (const float*)d_in[2];
  const float* w_la1 = (const float*)d_in[3];
  const float* w1_1  = (const float*)d_in[4];
  const float* w2_1  = (const float*)d_in[5];
  const float* w_la2 = (const float*)d_in[6];
  const float* w1_2  = (const float*)d_in[7];
  const float* w2_2  = (const float*)d_in[8];
  float* out0 = (float*)d_out;
  float* out1 = out0 + (size_t)BB * 3 * SS;

  char* wsp = (char*)d_ws;
  size_t off = 0;
  auto alloc = [&](size_t bytes) -> void* {
    void* p = wsp + off;
    off = (off + bytes + 255) & ~(size_t)255;
    return p;
  };
  float* hbuf = (float*)alloc((size_t)BB * SS * HHV * 4);  // 16 MB; also aliased as feaT (disjoint in time)
  float* feaT = hbuf;                                      // 8 MB needed, used only before hbuf
  int*   fpsi = (int*)alloc((size_t)BB * SS * 4);
  float* ncoor = (float*)alloc((size_t)BB * SS * 3 * 4);
  int*   gi = (int*)alloc((size_t)BB * SS * GG * 4);
  float* fa = (float*)alloc((size_t)BB * SS * C2V * 4);
  float* fb = (float*)alloc((size_t)BB * SS * C2V * 4);
  float* wsap = (float*)alloc(128 * 68 * 4);
  float* wla1p = (float*)alloc(128 * 132 * 4);
  float* wla2p = (float*)alloc(128 * 132 * 4);

  k_pad_w<<<dim3((128 * 68 + 255) / 256), dim3(256), 0, stream>>>(w_sa, wsap, 128, 67, 68);
  k_pad_w<<<dim3((128 * 132 + 255) / 256), dim3(256), 0, stream>>>(w_la1, wla1p, 128, 131, 132);
  k_pad_w<<<dim3((128 * 132 + 255) / 256), dim3(256), 0, stream>>>(w_la2, wla2p, 128, 131, 132);

  k_transpose_fea<<<dim3(NN / 32, CC / 32, BB), dim3(32, 8), 0, stream>>>(pfea, feaT);
  k_fps<<<dim3(BB), dim3(512), 0, stream>>>(pc, fpsi);
  k_gather<<<dim3((BB * SS + 255) / 256), dim3(256), 0, stream>>>(pc, fpsi, ncoor, out0);

  // stage 1: group among original N points, r=0.2
  k_knn<<<dim3(BB * SS), dim3(256), 0, stream>>>(pc, ncoor, 0, NN, 0.04f, gi);
  k_group_mlp<64><<<dim3(BB * SS / 16), dim3(256), 0, stream>>>(feaT, gi, ncoor, pc, 0, NN, 0.2f, wsap, fa);

  // shared grouping for both inv-res blocks (same points, same radius 0.4)
  k_knn<<<dim3(BB * SS), dim3(256), 0, stream>>>(ncoor, ncoor, 1, SS, 0.16f, gi);

  // inv-res block 1
  k_group_mlp<128><<<dim3(BB * SS / 16), dim3(256), 0, stream>>>(fa, gi, ncoor, ncoor, 1, SS, 0.4f, wla1p, fb);
  k_dense<false><<<dim3(128, 8), dim3(256), 0, stream>>>(fb, w1_1, nullptr, hbuf, 128, 512);
  k_dense<true><<<dim3(128, 2), dim3(256), 0, stream>>>(hbuf, w2_1, fa, fb, 512, 128);

  // inv-res block 2
  k_group_mlp<128><<<dim3(BB * SS / 16), dim3(256), 0, stream>>>(fb, gi, ncoor, ncoor, 1, SS, 0.4f, wla2p, fa);
  k_dense<false><<<dim3(128, 8), dim3(256), 0, stream>>>(fa, w1_2, nullptr, hbuf, 128, 512);
  k_dense<true><<<dim3(128, 2), dim3(256), 0, stream>>>(hbuf, w2_2, fb, fa, 512, 128);

  k_out1_t<<<dim3(SS / 32, 128 / 32, BB), dim3(32, 8), 0, stream>>>(fa, out1);
}

// Round 7
// 4061.188 us; speedup vs baseline: 1.4432x; 1.3052x over previous
//
#include <hip/hip_runtime.h>
#include <hip/hip_bf16.h>

#define BB 4
#define NN 8192
#define CC 64
#define SS 2048
#define GG 32
#define C2V 128
#define HHV 512

typedef unsigned long long u64;
typedef unsigned int u32;

// ---------------------------------------------------------------- transpose fea (B,C,N)->(B,N,C)
__global__ void k_transpose_fea(const float* __restrict__ in, float* __restrict__ out) {
  __shared__ float tile[32][33];
  const int b = blockIdx.z;
  const int n0 = blockIdx.x * 32, c0 = blockIdx.y * 32;
  const int tx = threadIdx.x, ty = threadIdx.y;
  const float* src = in + (size_t)b * CC * NN;
#pragma unroll
  for (int i = 0; i < 32; i += 8)
    tile[ty + i][tx] = src[(size_t)(c0 + ty + i) * NN + n0 + tx];
  __syncthreads();
  float* dst = out + (size_t)b * NN * CC;
#pragma unroll
  for (int i = 0; i < 32; i += 8)
    dst[(size_t)(n0 + ty + i) * CC + c0 + tx] = tile[tx][ty + i];
}

// ---------------------------------------------------------------- FPS (v3)
// 512 threads = 8 waves, 16 pts/lane held in NAMED float4 registers (no arrays ->
// no scratch demotion; rule #20). Squared-distance domain with ONE sqrt per lane
// per step: valid because correctly-rounded sqrt is monotone (min/max commute).
// np's first-index tie-break among sqrt-rounding-colliding points is reproduced
// exactly via the f64 preimage floor of s's rounding interval:
//   M = (pred(s)+s)/2 (exact in f64), L = M*M (exact: M has <=26 bits),
//   odd mantissa s => RN-even tie rounds DOWN => L += 1 ulp64,
//   Lf = ceil_to_f32(L);  {j : D2_j >= Lf} == {j : fl(sqrt(D2_j)) == s}.
__global__ __launch_bounds__(512) void k_fps(const float* __restrict__ pc, int* __restrict__ fps_idx) {
#pragma clang fp contract(off)
  const int b = blockIdx.x, tid = threadIdx.x;
  const int lane = tid & 63, wid = tid >> 6;
  const float* pb = pc + (size_t)b * 3 * NN;
  const float4* p4x = (const float4*)pb;
  const float4* p4y = (const float4*)(pb + NN);
  const float4* p4z = (const float4*)(pb + 2 * NN);
  float4 X0 = p4x[tid * 4 + 0], X1 = p4x[tid * 4 + 1], X2 = p4x[tid * 4 + 2], X3 = p4x[tid * 4 + 3];
  float4 Y0 = p4y[tid * 4 + 0], Y1 = p4y[tid * 4 + 1], Y2 = p4y[tid * 4 + 2], Y3 = p4y[tid * 4 + 3];
  float4 Z0 = p4z[tid * 4 + 0], Z1 = p4z[tid * 4 + 1], Z2 = p4z[tid * 4 + 2], Z3 = p4z[tid * 4 + 3];
  float4 D0 = make_float4(1e20f, 1e20f, 1e20f, 1e20f);
  float4 D1 = D0, D2q = D0, D3 = D0;

  __shared__ u64 sK[2][8];
  if (lane == 0)
    sK[0][wid] = (wid == 0) ? ((((u64)0xFFFFFFFFu) << 32) | (u64)0xFFFFFFFFu) : 0ull;
  __syncthreads();

#define DPPK64(K, CTL) { \
      u32 lo = (u32)(K), hi = (u32)((K) >> 32); \
      u32 lo2 = (u32)__builtin_amdgcn_update_dpp(0, (int)lo, CTL, 0xf, 0xf, false); \
      u32 hi2 = (u32)__builtin_amdgcn_update_dpp(0, (int)hi, CTL, 0xf, 0xf, false); \
      u64 k2 = ((u64)hi2 << 32) | (u64)lo2; if (k2 > (K)) (K) = k2; }
#define RMAXF(V, CTL) { \
      float t_ = __int_as_float(__builtin_amdgcn_update_dpp(0, __float_as_int(V), CTL, 0xf, 0xf, false)); \
      (V) = fmaxf((V), t_); }
#define RMINU(V, CTL) { \
      u32 t_ = (u32)__builtin_amdgcn_update_dpp(0, (int)(V), CTL, 0xf, 0xf, false); \
      (V) = min((V), t_); }

  for (int k = 0; k < SS; ++k) {
    const int p = k & 1;
    // ---- cross-wave reduce of 8 published keys (slots repeat every 8 lanes)
    u64 kk = sK[p][lane & 7];
    DPPK64(kk, 0x121) DPPK64(kk, 0x122) DPPK64(kk, 0x124)
    const int g = (int)(0xFFFFFFFFu - (u32)kk);
    if (tid == 0) fps_idx[b * SS + k] = g;
    const float cx = pb[g], cy = pb[NN + g], cz = pb[2 * NN + g];

    // ---- squared-distance update (bitwise np: materialized squares, (t0+t1)+t2)
#define UPDC(XX, YY, ZZ, DD) { \
      float dx_ = (XX) - cx, dy_ = (YY) - cy, dz_ = (ZZ) - cz; \
      float t0_ = dx_ * dx_, t1_ = dy_ * dy_, t2_ = dz_ * dz_; \
      float s_ = (t0_ + t1_) + t2_; \
      (DD) = fminf((DD), s_); }
    UPDC(X0.x, Y0.x, Z0.x, D0.x) UPDC(X0.y, Y0.y, Z0.y, D0.y)
    UPDC(X0.z, Y0.z, Z0.z, D0.z) UPDC(X0.w, Y0.w, Z0.w, D0.w)
    UPDC(X1.x, Y1.x, Z1.x, D1.x) UPDC(X1.y, Y1.y, Z1.y, D1.y)
    UPDC(X1.z, Y1.z, Z1.z, D1.z) UPDC(X1.w, Y1.w, Z1.w, D1.w)
    UPDC(X2.x, Y2.x, Z2.x, D2q.x) UPDC(X2.y, Y2.y, Z2.y, D2q.y)
    UPDC(X2.z, Y2.z, Z2.z, D2q.z) UPDC(X2.w, Y2.w, Z2.w, D2q.w)
    UPDC(X3.x, Y3.x, Z3.x, D3.x) UPDC(X3.y, Y3.y, Z3.y, D3.y)
    UPDC(X3.z, Y3.z, Z3.z, D3.z) UPDC(X3.w, Y3.w, Z3.w, D3.w)
#undef UPDC

    // ---- per-lane max of squared dists, single sqrt
    float m2 = fmaxf(
        fmaxf(fmaxf(fmaxf(D0.x, D0.y), fmaxf(D0.z, D0.w)),
              fmaxf(fmaxf(D1.x, D1.y), fmaxf(D1.z, D1.w))),
        fmaxf(fmaxf(fmaxf(D2q.x, D2q.y), fmaxf(D2q.z, D2q.w)),
              fmaxf(fmaxf(D3.x, D3.y), fmaxf(D3.z, D3.w))));
    float s = sqrtf(m2);

    // ---- exact preimage floor of s's rounding interval (f64, all steps exact)
    u32 sbits = __float_as_uint(s);
    float spred = __uint_as_float(sbits - 1u);
    double M = ((double)spred + (double)s) * 0.5;
    double L = M * M;
    if (sbits & 1u) L = __longlong_as_double(__double_as_longlong(L) + 1ll);
    float Lf = (float)L;
    if ((double)Lf < L) Lf = __uint_as_float(__float_as_uint(Lf) + 1u);

    // ---- smallest j with D2_j >= Lf (descending cascade => first-index)
    int jsel = 0;
    jsel = (D3.w >= Lf) ? 15 : jsel; jsel = (D3.z >= Lf) ? 14 : jsel;
    jsel = (D3.y >= Lf) ? 13 : jsel; jsel = (D3.x >= Lf) ? 12 : jsel;
    jsel = (D2q.w >= Lf) ? 11 : jsel; jsel = (D2q.z >= Lf) ? 10 : jsel;
    jsel = (D2q.y >= Lf) ? 9 : jsel; jsel = (D2q.x >= Lf) ? 8 : jsel;
    jsel = (D1.w >= Lf) ? 7 : jsel; jsel = (D1.z >= Lf) ? 6 : jsel;
    jsel = (D1.y >= Lf) ? 5 : jsel; jsel = (D1.x >= Lf) ? 4 : jsel;
    jsel = (D0.w >= Lf) ? 3 : jsel; jsel = (D0.z >= Lf) ? 2 : jsel;
    jsel = (D0.y >= Lf) ? 1 : jsel; jsel = (D0.x >= Lf) ? 0 : jsel;

    // ---- in-wave 2-phase reduce: f32 max of s, then u32 min index among ties
    float sm = s;
    RMAXF(sm, 0x121) RMAXF(sm, 0x122) RMAXF(sm, 0x124) RMAXF(sm, 0x128)
    sm = fmaxf(sm, __shfl_xor(sm, 16, 64));
    sm = fmaxf(sm, __shfl_xor(sm, 32, 64));
    u32 enc = (s == sm) ? (u32)(tid * 16 + jsel) : 0xFFFFFFFFu;
    RMINU(enc, 0x121) RMINU(enc, 0x122) RMINU(enc, 0x124) RMINU(enc, 0x128)
    enc = min(enc, (u32)__shfl_xor((int)enc, 16, 64));
    enc = min(enc, (u32)__shfl_xor((int)enc, 32, 64));

    u64 key = (((u64)__float_as_uint(sm)) << 32) | (u64)(0xFFFFFFFFu - enc);
    if (lane == 0) sK[p ^ 1][wid] = key;
    __syncthreads();  // single barrier per step (double-buffered keys)
  }
#undef DPPK64
#undef RMAXF
#undef RMINU
}

// ---------------------------------------------------------------- gather new_coor + out0
__global__ void k_gather(const float* __restrict__ pc, const int* __restrict__ fps_idx,
                         float* __restrict__ ncoor, float* __restrict__ out0) {
  int t = blockIdx.x * 256 + threadIdx.x;
  if (t >= BB * SS) return;
  int b = t / SS, s = t % SS;
  int id = fps_idx[t];
  const float* base = pc + (size_t)b * 3 * NN;
  float x = base[id], y = base[NN + id], z = base[2 * NN + id];
  ncoor[(size_t)t * 3] = x; ncoor[(size_t)t * 3 + 1] = y; ncoor[(size_t)t * 3 + 2] = z;
  size_t o = (size_t)b * 3 * SS + s;
  out0[o] = x; out0[o + SS] = y; out0[o + 2 * SS] = z;
}

// ---------------------------------------------------------------- kNN (k=32 within radius, fill with argmin)
// Distance replicates np's _sqdist bit-for-bit:
//   dot: np.einsum inner sum-of-products loop -> gcc -ffp-contract=fast -> FMA chain
//        acc = fma(a2,b2, fma(a1,b1, a0*b0))
//   norms: np.sum(x**2,-1) over a MATERIALIZED squares array -> pure sequential adds (no FMA)
//   d = ((-2*dot) + ||q||^2) + ||p||^2  (sequential adds, f32 throughout)
__global__ __launch_bounds__(256) void k_knn(const float* __restrict__ candp,
                                             const float* __restrict__ newc,
                                             int mode, int ncand, float r2,
                                             int* __restrict__ gidx) {
  __shared__ float cd[2048];
  __shared__ int ci[2048];
  __shared__ int hist[64];
  __shared__ int cnt, oc, binT, mlow;
  const int q = blockIdx.x, tid = threadIdx.x;
  const int b = q / SS;
  if (tid == 0) { cnt = 0; oc = 0; }
  if (tid < 64) hist[tid] = 0;
  __syncthreads();
  const float qx = newc[(size_t)q * 3], qy = newc[(size_t)q * 3 + 1], qz = newc[(size_t)q * 3 + 2];
  float qn;
  {
#pragma clang fp contract(off)
    qn = (qx * qx + qy * qy) + qz * qz;
  }
  const float sc = 64.0f / r2;
  const float* base = (mode == 0) ? candp + (size_t)b * 3 * NN : candp + (size_t)b * SS * 3;
  for (int i = tid; i < ncand; i += 256) {
    float x, y, z;
    if (mode == 0) { x = base[i]; y = base[NN + i]; z = base[2 * NN + i]; }
    else { x = base[3 * i]; y = base[3 * i + 1]; z = base[3 * i + 2]; }
    // FMA-chain dot (np einsum), contract-off norms (np materialized squares)
    float dot = fmaf(qz, z, fmaf(qy, y, qx * x));
    float d;
    {
#pragma clang fp contract(off)
      float pn = (x * x + y * y) + z * z;
      d = ((-2.0f * dot) + qn) + pn;
    }
    if (d <= r2) {
      int pp = atomicAdd(&cnt, 1);
      if (pp < 2048) { cd[pp] = d; ci[pp] = i; }
      float db = (d > 0.0f) ? d : 0.0f;
      atomicAdd(&hist[min(63, (int)(db * sc))], 1);
    }
  }
  __syncthreads();
  const int M = min(cnt, 2048);
  if (tid == 0) {
    if (M > 32) {
      int c = 0, t = 0;
      for (t = 0; t < 64; ++t) { if (c + hist[t] >= 32) break; c += hist[t]; }
      binT = t; mlow = c;
    } else binT = -1;
  }
  __syncthreads();
  int* out = gidx + (size_t)q * 32;
  if (binT < 0) {
    for (int j = tid; j < M; j += 256) out[atomicAdd(&oc, 1)] = ci[j];
    __syncthreads();
    if (tid == 0 && M < 32) {
      float bd = 1e30f; int bx = 0x7FFFFFFF;
      for (int j = 0; j < M; ++j)
        if (cd[j] < bd || (cd[j] == bd && ci[j] < bx)) { bd = cd[j]; bx = ci[j]; }
      for (int j = M; j < 32; ++j) out[j] = bx;
    }
  } else {
    const int bt = binT, m = mlow;
    for (int j = tid; j < M; j += 256) {
      float dbj = (cd[j] > 0.0f) ? cd[j] : 0.0f;
      int bin = min(63, (int)(dbj * sc));
      if (bin < bt) out[atomicAdd(&oc, 1)] = ci[j];
      else if (bin == bt) {
        int r = 0; const float dj = cd[j]; const int ij = ci[j];
        for (int kk = 0; kk < M; ++kk) {
          float dbk = (cd[kk] > 0.0f) ? cd[kk] : 0.0f;
          if (min(63, (int)(dbk * sc)) == bt &&
              (cd[kk] < dj || (cd[kk] == dj && ci[kk] < ij))) ++r;
        }
        if (m + r < 32) out[m + r] = ci[j];
      }
    }
  }
}

// ---------------------------------------------------------------- grouped MLP + max  (out 128 ch)
template <int FDIM>
__global__ __launch_bounds__(256) void k_group_mlp(
    const float* __restrict__ fea, const int* __restrict__ gidx,
    const float* __restrict__ newc, const float* __restrict__ candp,
    int mode, int ncand, float radius,
    const float* __restrict__ wp, float* __restrict__ outf) {
  constexpr int CP4 = FDIM + 4;     // padded cols (67->68, 131->132)
  constexpr int NC4 = CP4 / 4;
  __shared__ float4 g4[2][32][NC4];
  __shared__ int sidx[2][32];
  __shared__ float sq[2][3];
  __shared__ float pf[2][4][128];
  const int tid = threadIdx.x;
  const int rs = tid >> 7, tl = tid & 127;
  const int dt = tl & 31, et = tl >> 5;
  const int d0 = dt * 4, e0 = et * 8;
  const int row0 = blockIdx.x * 16;
  for (int rp = 0; rp < 16; rp += 2) {
    const int row = row0 + rp + rs;
    if (tl < 32) sidx[rs][tl] = gidx[(size_t)row * 32 + tl];
    if (tl < 3) sq[rs][tl] = newc[(size_t)row * 3 + tl];
    __syncthreads();
    const int bb2 = row / SS;
    const float* fb = fea + (size_t)bb2 * ncand * FDIM;
    const float* cb = (mode == 0) ? candp + (size_t)bb2 * 3 * NN
                                  : candp + (size_t)bb2 * SS * 3;
    float* gf = (float*)&g4[rs][0][0];
    for (int qq = tl; qq < 32 * CP4; qq += 128) {
      int e = qq / CP4, c = qq - e * CP4;
      int id = sidx[rs][e];
      float v;
      if (c < FDIM) v = fb[(size_t)id * FDIM + c];
      else if (c < FDIM + 3) {
        int comp = c - FDIM;
        float pcv = (mode == 0) ? cb[(size_t)comp * NN + id] : cb[(size_t)id * 3 + comp];
        v = (pcv - sq[rs][comp]) / radius;
      } else v = 0.0f;
      gf[qq] = v;
    }
    __syncthreads();
    float acc[4][8];
#pragma unroll
    for (int i = 0; i < 4; ++i)
#pragma unroll
      for (int j = 0; j < 8; ++j) acc[i][j] = 0.0f;
    const float4* w4 = (const float4*)wp;
    for (int c4 = 0; c4 < NC4; ++c4) {
      float4 wv[4], gv[8];
#pragma unroll
      for (int i = 0; i < 4; ++i) wv[i] = w4[(size_t)(d0 + i) * NC4 + c4];
#pragma unroll
      for (int j = 0; j < 8; ++j) gv[j] = g4[rs][e0 + j][c4];
#pragma unroll
      for (int i = 0; i < 4; ++i)
#pragma unroll
        for (int j = 0; j < 8; ++j) {
          acc[i][j] += wv[i].x * gv[j].x;
          acc[i][j] += wv[i].y * gv[j].y;
          acc[i][j] += wv[i].z * gv[j].z;
          acc[i][j] += wv[i].w * gv[j].w;
        }
    }
#pragma unroll
    for (int i = 0; i < 4; ++i) {
      float m = acc[i][0];
#pragma unroll
      for (int j = 1; j < 8; ++j) m = fmaxf(m, acc[i][j]);
      pf[rs][et][d0 + i] = m;
    }
    __syncthreads();
    {
      const int d = tid & 127, r2s = tid >> 7;
      const int rowW = row0 + rp + r2s;
      float m = fmaxf(fmaxf(pf[r2s][0][d], pf[r2s][1][d]),
                      fmaxf(pf[r2s][2][d], pf[r2s][3][d]));
      outf[(size_t)rowW * 128 + d] = fmaxf(m, 0.0f);
    }
    __syncthreads();
  }
}

// ---------------------------------------------------------------- dense GEMM: Out = relu(A(M,K) * W(N,K)^T [+ Id])
template <bool RESID>
__global__ __launch_bounds__(256) void k_dense(
    const float* __restrict__ A, const float* __restrict__ W,
    const float* __restrict__ Id, float* __restrict__ Out,
    int K, int Ntot) {
  __shared__ float4 sa[64][17], sb[64][17];
  const int m0 = blockIdx.x * 64, n0 = blockIdx.y * 64;
  const int tid = threadIdx.x;
  const int mt = tid & 15, nt = tid >> 4;
  float acc[4][4];
#pragma unroll
  for (int i = 0; i < 4; ++i)
#pragma unroll
    for (int j = 0; j < 4; ++j) acc[i][j] = 0.0f;
  for (int kc = 0; kc < K; kc += 64) {
    for (int q2 = tid; q2 < 2048; q2 += 256) {
      int half = q2 >> 10, qq = q2 & 1023;
      int r = qq >> 4, c = qq & 15;
      const float* src = half ? (W + (size_t)(n0 + r) * K + kc + c * 4)
                              : (A + (size_t)(m0 + r) * K + kc + c * 4);
      float4 v = *(const float4*)src;
      if (half) sb[r][c] = v; else sa[r][c] = v;
    }
    __syncthreads();
#pragma unroll
    for (int c = 0; c < 16; ++c) {
      const int ks = (c + mt + nt) & 15;  // swizzle to break LDS bank conflicts
      float4 av[4], bv[4];
#pragma unroll
      for (int i = 0; i < 4; ++i) av[i] = sa[mt * 4 + i][ks];
#pragma unroll
      for (int j = 0; j < 4; ++j) bv[j] = sb[nt * 4 + j][ks];
#pragma unroll
      for (int i = 0; i < 4; ++i)
#pragma unroll
        for (int j = 0; j < 4; ++j) {
          acc[i][j] += av[i].x * bv[j].x;
          acc[i][j] += av[i].y * bv[j].y;
          acc[i][j] += av[i].z * bv[j].z;
          acc[i][j] += av[i].w * bv[j].w;
        }
    }
    __syncthreads();
  }
#pragma unroll
  for (int i = 0; i < 4; ++i)
#pragma unroll
    for (int j = 0; j < 4; ++j) {
      size_t o = (size_t)(m0 + mt * 4 + i) * Ntot + n0 + nt * 4 + j;
      float v = acc[i][j];
      if (RESID) v += Id[o];
      Out[o] = fmaxf(v, 0.0f);
    }
}

// ---------------------------------------------------------------- pad weights rows to 4-aligned cols
__global__ void k_pad_w(const float* __restrict__ src, float* __restrict__ dst,
                        int rows, int cin, int cp4) {
  int t = blockIdx.x * 256 + threadIdx.x;
  if (t >= rows * cp4) return;
  int r = t / cp4, c = t - r * cp4;
  dst[t] = (c < cin) ? src[(size_t)r * cin + c] : 0.0f;
}

// ---------------------------------------------------------------- out1 transpose (B*S,128) -> (B,128,S)
__global__ void k_out1_t(const float* __restrict__ in, float* __restrict__ out) {
  __shared__ float tile[32][33];
  const int b = blockIdx.z;
  const int s0 = blockIdx.x * 32, d0 = blockIdx.y * 32;
  const int tx = threadIdx.x, ty = threadIdx.y;
#pragma unroll
  for (int i = 0; i < 32; i += 8)
    tile[ty + i][tx] = in[(size_t)(b * SS + s0 + ty + i) * 128 + d0 + tx];
  __syncthreads();
#pragma unroll
  for (int i = 0; i < 32; i += 8)
    out[(size_t)(b * 128 + d0 + ty + i) * SS + s0 + tx] = tile[tx][ty + i];
}

// ----------------------------------------------------------------
extern "C" void kernel_launch(void* const* d_in, const int* in_sizes, int n_in,
                              void* d_out, int out_size, void* d_ws, size_t ws_size,
                              hipStream_t stream) {
  const float* pc    = (const float*)d_in[0];
  const float* pfea  = (const float*)d_in[1];
  const float* w_sa  = (const float*)d_in[2];
  const float* w_la1 = (const float*)d_in[3];
  const float* w1_1  = (const float*)d_in[4];
  const float* w2_1  = (const float*)d_in[5];
  const float* w_la2 = (const float*)d_in[6];
  const float* w1_2  = (const float*)d_in[7];
  const float* w2_2  = (const float*)d_in[8];
  float* out0 = (float*)d_out;
  float* out1 = out0 + (size_t)BB * 3 * SS;

  char* wsp = (char*)d_ws;
  size_t off = 0;
  auto alloc = [&](size_t bytes) -> void* {
    void* p = wsp + off;
    off = (off + bytes + 255) & ~(size_t)255;
    return p;
  };
  float* hbuf = (float*)alloc((size_t)BB * SS * HHV * 4);  // 16 MB; also aliased as feaT (disjoint in time)
  float* feaT = hbuf;                                      // 8 MB needed, used only before hbuf
  int*   fpsi = (int*)alloc((size_t)BB * SS * 4);
  float* ncoor = (float*)alloc((size_t)BB * SS * 3 * 4);
  int*   gi = (int*)alloc((size_t)BB * SS * GG * 4);
  float* fa = (float*)alloc((size_t)BB * SS * C2V * 4);
  float* fb = (float*)alloc((size_t)BB * SS * C2V * 4);
  float* wsap = (float*)alloc(128 * 68 * 4);
  float* wla1p = (float*)alloc(128 * 132 * 4);
  float* wla2p = (float*)alloc(128 * 132 * 4);

  k_pad_w<<<dim3((128 * 68 + 255) / 256), dim3(256), 0, stream>>>(w_sa, wsap, 128, 67, 68);
  k_pad_w<<<dim3((128 * 132 + 255) / 256), dim3(256), 0, stream>>>(w_la1, wla1p, 128, 131, 132);
  k_pad_w<<<dim3((128 * 132 + 255) / 256), dim3(256), 0, stream>>>(w_la2, wla2p, 128, 131, 132);

  k_transpose_fea<<<dim3(NN / 32, CC / 32, BB), dim3(32, 8), 0, stream>>>(pfea, feaT);
  k_fps<<<dim3(BB), dim3(512), 0, stream>>>(pc, fpsi);
  k_gather<<<dim3((BB * SS + 255) / 256), dim3(256), 0, stream>>>(pc, fpsi, ncoor, out0);

  // stage 1: group among original N points, r=0.2
  k_knn<<<dim3(BB * SS), dim3(256), 0, stream>>>(pc, ncoor, 0, NN, 0.04f, gi);
  k_group_mlp<64><<<dim3(BB * SS / 16), dim3(256), 0, stream>>>(feaT, gi, ncoor, pc, 0, NN, 0.2f, wsap, fa);

  // shared grouping for both inv-res blocks (same points, same radius 0.4)
  k_knn<<<dim3(BB * SS), dim3(256), 0, stream>>>(ncoor, ncoor, 1, SS, 0.16f, gi);

  // inv-res block 1
  k_group_mlp<128><<<dim3(BB * SS / 16), dim3(256), 0, stream>>>(fa, gi, ncoor, ncoor, 1, SS, 0.4f, wla1p, fb);
  k_dense<false><<<dim3(128, 8), dim3(256), 0, stream>>>(fb, w1_1, nullptr, hbuf, 128, 512);
  k_dense<true><<<dim3(128, 2), dim3(256), 0, stream>>>(hbuf, w2_1, fa, fb, 512, 128);

  // inv-res block 2
  k_group_mlp<128><<<dim3(BB * SS / 16), dim3(256), 0, stream>>>(fb, gi, ncoor, ncoor, 1, SS, 0.4f, wla2p, fa);
  k_dense<false><<<dim3(128, 8), dim3(256), 0, stream>>>(fa, w1_2, nullptr, hbuf, 128, 512);
  k_dense<true><<<dim3(128, 2), dim3(256), 0, stream>>>(hbuf, w2_2, fb, fa, 512, 128);

  k_out1_t<<<dim3(SS / 32, 128 / 32, BB), dim3(32, 8), 0, stream>>>(fa, out1);
}